// Round 4
// baseline (244.623 us; speedup 1.0000x reference)
//
#include <hip/hip_runtime.h>
#include <hip/hip_bf16.h>

// SrnmSpmm: out[b,s,n] = sum_k x[b,s,keep[k]] * values[n,k] + bias[n]
// keep: cols {8i, 8i+2} of D_IN=4096 -> K=1024. M = B*S = 16384, N = 4096.
//
// R4: GEMM re-pipelined: BK=32, 4-deep LDS ring (4 x 32KiB), stage issued 3
// K-steps ahead (~3700 cyc window > HBM latency), vmcnt(8)/step, vmcnt(63)
// for the 2 steps after each epilogue (store-drain in background).
// Prep v2: one 64B line per lane (coalesced).

#define M_TOTAL 16384
#define DIN     4096
#define KDIM    1024
#define NDIM    4096

typedef unsigned short u16;
typedef unsigned int   u32;
typedef __bf16 bf16x8 __attribute__((ext_vector_type(8)));
typedef float  f32x4  __attribute__((ext_vector_type(4)));

typedef const void __attribute__((address_space(1)))* gp_t;
typedef void __attribute__((address_space(3)))*       lp_t;

__device__ __forceinline__ u16 f2bf(float f) {
    u32 u = __float_as_uint(f);
    u += 0x7FFFu + ((u >> 16) & 1u);   // round-to-nearest-even
    return (u16)(u >> 16);
}
__device__ __forceinline__ u32 pack2(float a, float b) {
    return (u32)f2bf(a) | ((u32)f2bf(b) << 16);
}

// Pass 1: blocks [0,4096): compact x — each lane owns one 64B line (2 x
// 8-block): float4 @ +0 and @ +32B -> uint2 (kept cols 0,2 of each block).
// Blocks [4096,6144): cast values, 8 floats/lane -> uint4.
__global__ void prep_kernel(const float* __restrict__ x, uint2* __restrict__ xg2,
                            const float* __restrict__ vals, uint4* __restrict__ vb4) {
    const int tid = threadIdx.x;
    if (blockIdx.x < 4096) {
        int i = blockIdx.x * 256 + tid;
        const int stride = 4096 * 256;     // 4,194,304 lines = 4*stride exact
#pragma unroll
        for (int it = 0; it < 4; ++it, i += stride) {
            const float* p = x + (size_t)i * 16;
            float4 f0 = *(const float4*)p;
            float4 f1 = *(const float4*)(p + 8);
            xg2[i] = make_uint2(pack2(f0.x, f0.z), pack2(f1.x, f1.z));
        }
    } else {
        const int i = (blockIdx.x - 4096) * 256 + tid;   // [0, 524288)
        const float* p = vals + (size_t)i * 8;
        float4 a = *(const float4*)p;
        float4 b = *(const float4*)(p + 4);
        vb4[i] = make_uint4(pack2(a.x, a.y), pack2(a.z, a.w),
                            pack2(b.x, b.y), pack2(b.z, b.w));
    }
}

// ---------------- persistent 256x256 bf16 GEMM, BK=32, 4-deep ring ----------
// 512 threads = 8 waves (2M x 4N); wave tile 128x64. K-step = 32.
// Per K-step: A-tile 256x32 bf16 = 16 KiB, B-tile 16 KiB; ring buf b:
// A @ b*32K, B @ b*32K+16K. Subtile [16 rows][32 cols] = 1 KiB, st-swizzle:
// byte = sub*1024 + (row&15)*64 + col*2, XOR bit5 <- row-bit-3. gload dest
// linear (source pre-swizzled). Stage for step t issued during step t-3;
// vmcnt(8) (= 2 newest stages outstanding) guarantees step t+1's buffer.

#define ABASE(bc) ((bc) * 32768)
#define BBASE(bc) ((bc) * 32768 + 16384)

#define LOADA(bc, mh) { _Pragma("unroll") \
    for (int m_ = 0; m_ < 4; ++m_) \
        af[m_] = *(const bf16x8*)(lds + ABASE(bc) + (wr * 8 + (mh) * 4 + m_) * 1024 + fl_off); }

#define LOADB(bc) { _Pragma("unroll") \
    for (int n_ = 0; n_ < 4; ++n_) \
        bfr[n_] = *(const bf16x8*)(lds + BBASE(bc) + (wc * 4 + n_) * 1024 + fl_off); }

#define MFMA16(mh) { \
    __builtin_amdgcn_s_setprio(1); \
    _Pragma("unroll") for (int m_ = 0; m_ < 4; ++m_) \
    _Pragma("unroll") for (int n_ = 0; n_ < 4; ++n_) \
        acc[(mh) * 4 + m_][n_] = __builtin_amdgcn_mfma_f32_16x16x32_bf16( \
            af[m_], bfr[n_], acc[(mh) * 4 + m_][n_], 0, 0, 0); \
    __builtin_amdgcn_s_setprio(0); }

#define SA(bc, src, ko) { \
    __builtin_amdgcn_global_load_lds((gp_t)((src) + (ko)), \
        (lp_t)(lds + ABASE(bc) + dst0), 16, 0, 0); \
    __builtin_amdgcn_global_load_lds((gp_t)((src) + 128 * KDIM + (ko)), \
        (lp_t)(lds + ABASE(bc) + 8192 + dst0), 16, 0, 0); }

#define SB(bc, ko) { \
    __builtin_amdgcn_global_load_lds((gp_t)(Bs0 + (ko)), \
        (lp_t)(lds + BBASE(bc) + dst0), 16, 0, 0); \
    __builtin_amdgcn_global_load_lds((gp_t)(Bs0 + 128 * KDIM + (ko)), \
        (lp_t)(lds + BBASE(bc) + 8192 + dst0), 16, 0, 0); }

#define BAR() __builtin_amdgcn_s_barrier()
#define VMCNT8()  asm volatile("s_waitcnt vmcnt(8)"  ::: "memory")
#define VMCNT63() asm volatile("s_waitcnt vmcnt(63)" ::: "memory")
#define W01 { if (r == 0) { VMCNT8(); } else { VMCNT63(); } }

// One K-step on ring buffer bc; SAx/SBx stage step (current+3); W = end wait.
#define STEP(bc, SAx, SBx, W) { \
    LOADB(bc); LOADA(bc, 0); SAx; BAR(); MFMA16(0); BAR(); \
    LOADA(bc, 1); SBx; W; BAR(); MFMA16(1); BAR(); }

__global__ __launch_bounds__(512, 2) void gemm_kernel(
    const u16* __restrict__ A, const u16* __restrict__ Bv,
    const float* __restrict__ bias, float* __restrict__ C)
{
    __shared__ __align__(1024) char lds[131072];

    const int tid  = threadIdx.x;
    const int lane = tid & 63;
    const int wid  = tid >> 6;
    const int wr   = wid >> 2;      // 0..1
    const int wc   = wid & 3;       // 0..3
    const int lrow = lane & 15;
    const int lg   = lane >> 4;     // 0..3

    // Persistent mapping: XCD (bb&7) covers btm {8c..8c+7}; btn fixed/block.
    const int bb   = blockIdx.x;
    const int btm0 = (bb & 7) * 8 + (bb >> 7);
    const int btn  = (bb >> 3) & 15;

    // Staging source (pre-swizzled global addr; LDS dest linear).
    const int st_r0 = wid * 16 + (lane >> 2);
    const int st_ck = ((lane & 3) * 8) ^ ((lane & 32) >> 1);
    const u16* A0  = A  + (size_t)(btm0 * 256 + st_r0) * KDIM + st_ck;
    const u16* Bs0 = Bv + (size_t)(btn  * 256 + st_r0) * KDIM + st_ck;
    const int dst0 = tid * 16;

    // Fragment ds_read offset within a 16KiB tile (subtiled + swizzled).
    const int fl_off = lrow * 64 + ((lg * 16) ^ (((lrow >> 3) & 1) << 5));

    // bias loop-invariant (btn fixed).
    const int c_col0 = btn * 256 + wc * 64 + lrow;
    float bvr[4];
#pragma unroll
    for (int n = 0; n < 4; ++n) bvr[n] = bias[c_col0 + n * 16];

    f32x4 acc[8][4] = {};
    bf16x8 af[4], bfr[4];

    // Prologue: stage K-steps 0,1,2 of tile 0.
    SA(0, A0, 0);   SB(0, 0);
    SA(1, A0, 32);  SB(1, 32);
    SA(2, A0, 64);  SB(2, 64);
    VMCNT8();                    // step 0 landed (2 newest stages in flight)
    BAR();

#pragma unroll 1
    for (int r = 0; r < 4; ++r) {
        const u16* Ar = A0 + (size_t)r * 512 * KDIM;
        const u16* An = (r < 3) ? (Ar + 512 * KDIM) : Ar;  // r=3: dummy re-stage

        // u=0: steps 0..3, staging steps 3..6. Steps 0,1 use vmcnt(63) when
        // r>0 (epilogue stores of tile r-1 still in queue; the needed stage
        // has >63 instructions after it, so 63 still guarantees it landed).
        STEP(0, SA(3, Ar, 96),  SB(3, 96),  W01);
        STEP(1, SA(0, Ar, 128), SB(0, 128), W01);
        STEP(2, SA(1, Ar, 160), SB(1, 160), VMCNT8());
        STEP(3, SA(2, Ar, 192), SB(2, 192), VMCNT8());

#pragma unroll 1
        for (int u = 1; u < 7; ++u) {
            const int ko = (4 * u + 3) * 32;
            STEP(0, SA(3, Ar, ko),      SB(3, ko),      VMCNT8());
            STEP(1, SA(0, Ar, ko + 32), SB(0, ko + 32), VMCNT8());
            STEP(2, SA(1, Ar, ko + 64), SB(1, ko + 64), VMCNT8());
            STEP(3, SA(2, Ar, ko + 96), SB(2, ko + 96), VMCNT8());
        }

        // u=7: steps 28..31; stages: 31 (this tile), then next tile's 0,1,2.
        STEP(0, SA(3, Ar, 992), SB(3, 992), VMCNT8());
        STEP(1, SA(0, An, 0),   SB(0, 0),   VMCNT8());
        STEP(2, SA(1, An, 32),  SB(1, 32),  VMCNT8());
        STEP(3, SA(2, An, 64),  SB(2, 64),  VMCNT8());

        // Epilogue tile r (next tile's first 3 buffers already in LDS/flight).
        const int c_row0 = (btm0 + 2 * r) * 256 + wr * 128 + lg * 4;
#pragma unroll
        for (int mi = 0; mi < 8; ++mi) {
            const int row = c_row0 + (mi >> 2) * 64 + (mi & 3) * 16;
#pragma unroll
            for (int n = 0; n < 4; ++n) {
#pragma unroll
                for (int j = 0; j < 4; ++j)
                    C[(size_t)(row + j) * NDIM + c_col0 + n * 16] = acc[mi][n][j] + bvr[n];
                acc[mi][n] = (f32x4){0.f, 0.f, 0.f, 0.f};
            }
        }
    }
}

extern "C" void kernel_launch(void* const* d_in, const int* in_sizes, int n_in,
                              void* d_out, int out_size, void* d_ws, size_t ws_size,
                              hipStream_t stream) {
    const float* x      = (const float*)d_in[0];
    const float* values = (const float*)d_in[1];
    const float* bias   = (const float*)d_in[2];
    float* out = (float*)d_out;

    // ws: xg bf16 [16384][1024] = 32 MB @ 0; values bf16 [4096][1024] @ 32 MB
    u16* xg = (u16*)d_ws;
    u16* vb = (u16*)((char*)d_ws + ((size_t)32 << 20));

    prep_kernel<<<6144, 256, 0, stream>>>(x, (uint2*)xg, values, (uint4*)vb);
    gemm_kernel<<<256, 512, 0, stream>>>(xg, vb, bias, out);
}

// Round 6
// 212.447 us; speedup vs baseline: 1.1515x; 1.1515x over previous
//
#include <hip/hip_runtime.h>
#include <hip/hip_bf16.h>

// SrnmSpmm: out[b,s,n] = sum_k x[b,s,keep[k]] * values[n,k] + bias[n]
// keep: cols {8i, 8i+2} of D_IN=4096 -> K=1024. M = B*S = 16384, N = 4096.
//
// R5b: = R3 schedule (persistent 256-block, BK=64, 2-deep dbuf, vmcnt(6))
// + NONTEMPORAL C stores (keep xg/vb L3-resident -> staging hits cache)
// + NT loads of x/values in prep (read-once streams don't pollute L3).
// (R5 compile fix: NT loads use ext_vector f32x4, not HIP float4.)

#define M_TOTAL 16384
#define DIN     4096
#define KDIM    1024
#define NDIM    4096

typedef unsigned short u16;
typedef unsigned int   u32;
typedef __bf16 bf16x8 __attribute__((ext_vector_type(8)));
typedef float  f32x4  __attribute__((ext_vector_type(4)));

typedef const void __attribute__((address_space(1)))* gp_t;
typedef void __attribute__((address_space(3)))*       lp_t;

__device__ __forceinline__ u16 f2bf(float f) {
    u32 u = __float_as_uint(f);
    u += 0x7FFFu + ((u >> 16) & 1u);   // round-to-nearest-even
    return (u16)(u >> 16);
}
__device__ __forceinline__ u32 pack2(float a, float b) {
    return (u32)f2bf(a) | ((u32)f2bf(b) << 16);
}

// Pass 1: blocks [0,4096): compact x — each lane owns one 64B line (2 x
// 8-block): f32x4 @ +0 and @ +32B -> uint2 (kept cols 0,2). NT loads.
// Blocks [4096,6144): cast values, 8 floats/lane -> uint4. NT loads.
__global__ void prep_kernel(const float* __restrict__ x, uint2* __restrict__ xg2,
                            const float* __restrict__ vals, uint4* __restrict__ vb4) {
    const int tid = threadIdx.x;
    if (blockIdx.x < 4096) {
        int i = blockIdx.x * 256 + tid;
        const int stride = 4096 * 256;     // 4,194,304 lines = 4*stride exact
#pragma unroll
        for (int it = 0; it < 4; ++it, i += stride) {
            const f32x4* p = (const f32x4*)(x + (size_t)i * 16);
            f32x4 f0 = __builtin_nontemporal_load(p);
            f32x4 f1 = __builtin_nontemporal_load(p + 2);
            xg2[i] = make_uint2(pack2(f0.x, f0.z), pack2(f1.x, f1.z));
        }
    } else {
        const int i = (blockIdx.x - 4096) * 256 + tid;   // [0, 524288)
        const f32x4* p = (const f32x4*)(vals + (size_t)i * 8);
        f32x4 a = __builtin_nontemporal_load(p);
        f32x4 b = __builtin_nontemporal_load(p + 1);
        vb4[i] = make_uint4(pack2(a.x, a.y), pack2(a.z, a.w),
                            pack2(b.x, b.y), pack2(b.z, b.w));
    }
}

// ---------------- persistent 256x256 8-phase bf16 GEMM (R3 schedule) -------
// 512 threads = 8 waves (2M x 4N); wave tile 128x64. K-tile 64 (2 K-halves).
// Half-tile 256x32 bf16 = 16 KiB = 2 gload_lds x 512thr x 16B.
// LDS 128 KiB: A[dbuf][kh] @ (2d+kh)*16K, B @ +64K. st_16x32 swizzle applied
// on global SOURCE (gload dest linear) and on ds_read addr. vmcnt(6) = all
// but newest 3 half-tiles landed, at phases 4 and 8 only.

#define LDSA(d, kh) (((d) * 2 + (kh)) * 16384)
#define LDSB(d, kh) (65536 + ((d) * 2 + (kh)) * 16384)

#define LOADA(d, kh, mh) { _Pragma("unroll") \
    for (int m_ = 0; m_ < 4; ++m_) \
        af[m_] = *(const bf16x8*)(lds + LDSA(d, kh) + (wr * 8 + (mh) * 4 + m_) * 1024 + fl_off); }

#define LOADB(d, kh) { _Pragma("unroll") \
    for (int n_ = 0; n_ < 4; ++n_) \
        bfr[n_] = *(const bf16x8*)(lds + LDSB(d, kh) + (wc * 4 + n_) * 1024 + fl_off); }

#define MFMA16(mh) { \
    __builtin_amdgcn_s_setprio(1); \
    _Pragma("unroll") for (int m_ = 0; m_ < 4; ++m_) \
    _Pragma("unroll") for (int n_ = 0; n_ < 4; ++n_) \
        acc[(mh) * 4 + m_][n_] = __builtin_amdgcn_mfma_f32_16x16x32_bf16( \
            af[m_], bfr[n_], acc[(mh) * 4 + m_][n_], 0, 0, 0); \
    __builtin_amdgcn_s_setprio(0); }

#define BAR() __builtin_amdgcn_s_barrier()
#define VMCNT6() asm volatile("s_waitcnt vmcnt(6)" ::: "memory")

__global__ __launch_bounds__(512, 2) void gemm_kernel(
    const u16* __restrict__ A, const u16* __restrict__ Bv,
    const float* __restrict__ bias, float* __restrict__ C)
{
    __shared__ __align__(1024) char lds[131072];

    const int tid  = threadIdx.x;
    const int lane = tid & 63;
    const int wid  = tid >> 6;
    const int wr   = wid >> 2;      // 0..1
    const int wc   = wid & 3;       // 0..3
    const int lrow = lane & 15;
    const int lg   = lane >> 4;     // 0..3

    // Persistent mapping: XCD (bb&7) covers btm {8c..8c+7}; btn fixed/block.
    const int bb   = blockIdx.x;
    const int btm0 = (bb & 7) * 8 + (bb >> 7);
    const int btn  = (bb >> 3) & 15;

    // Staging source (pre-swizzled global addr; LDS dest linear).
    const int st_r0 = wid * 16 + (lane >> 2);
    const int st_ck = ((lane & 3) * 8) ^ ((lane & 32) >> 1);
    const u16* A0  = A  + (size_t)(btm0 * 256 + st_r0) * KDIM + st_ck;
    const u16* Bs0 = Bv + (size_t)(btn  * 256 + st_r0) * KDIM + st_ck;
    const int dst0 = tid * 16;

    // Fragment ds_read offset within a half-tile (subtiled + swizzled).
    const int fl_off = lrow * 64 + ((lg * 16) ^ (((lrow >> 3) & 1) << 5));

    // half-tile s (within a tile): kt=s>>2, j=s&3 (0=A.kh0,1=B.kh0,2=A.kh1,3=B.kh1)
    auto STAGE = [&](const u16* as_, int s) {
        const int kt = s >> 2, j = s & 3;
        const int d = kt & 1, kh = (j >> 1) & 1;
        const int ko = kt * 64 + kh * 32;
        const u16* src = (j & 1) ? Bs0 : as_;
        const int base = ((j & 1) ? 65536 : 0) + (d * 2 + kh) * 16384;
        __builtin_amdgcn_global_load_lds((gp_t)(src + ko),
            (lp_t)(lds + base + dst0), 16, 0, 0);
        __builtin_amdgcn_global_load_lds((gp_t)(src + 128 * KDIM + ko),
            (lp_t)(lds + base + 8192 + dst0), 16, 0, 0);
    };

    // bias is loop-invariant (btn fixed): load once.
    const int c_col0 = btn * 256 + wc * 64 + lrow;
    float bvr[4];
#pragma unroll
    for (int n = 0; n < 4; ++n) bvr[n] = bias[c_col0 + n * 16];

    f32x4 acc[8][4] = {};
    bf16x8 af[4], bfr[4];

    // Prologue (once): stage K-tile 0 fully + 3 half-tiles of K-tile 1.
    STAGE(A0, 0); STAGE(A0, 1); STAGE(A0, 2); STAGE(A0, 3);
    STAGE(A0, 4); STAGE(A0, 5); STAGE(A0, 6);
    VMCNT6();                    // s0..s3 landed
    BAR();

#pragma unroll 1
    for (int r = 0; r < 4; ++r) {
        const u16* Ar = A0 + (size_t)r * 512 * KDIM;
        const u16* An = (r < 3) ? (Ar + 512 * KDIM) : Ar;  // r=3: dummy re-stage

#pragma unroll 1
        for (int t = 0; t < 7; ++t) {
            const int s0 = 8 * t + 7;
            // ---- K-tile 2t (dbuf 0) ----
            LOADB(0, 0); LOADA(0, 0, 0); STAGE(Ar, s0);     BAR(); MFMA16(0); BAR();
            LOADA(0, 0, 1);              STAGE(Ar, s0 + 1); BAR(); MFMA16(1); BAR();
            LOADB(0, 1); LOADA(0, 1, 0); STAGE(Ar, s0 + 2); BAR(); MFMA16(0); BAR();
            LOADA(0, 1, 1);              STAGE(Ar, s0 + 3); BAR(); MFMA16(1);
            VMCNT6(); BAR();
            // ---- K-tile 2t+1 (dbuf 1) ----
            LOADB(1, 0); LOADA(1, 0, 0); STAGE(Ar, s0 + 4); BAR(); MFMA16(0); BAR();
            LOADA(1, 0, 1);              STAGE(Ar, s0 + 5); BAR(); MFMA16(1); BAR();
            LOADB(1, 1); LOADA(1, 1, 0); STAGE(Ar, s0 + 6); BAR(); MFMA16(0); BAR();
            LOADA(1, 1, 1);              STAGE(Ar, s0 + 7); BAR(); MFMA16(1);
            VMCNT6(); BAR();
        }
        // ---- tail: K-tiles 14 (dbuf 0) & 15 (dbuf 1); stage slots:
        // s63 (this tile) then n0..n6 (next tile).
        LOADB(0, 0); LOADA(0, 0, 0); STAGE(Ar, 63); BAR(); MFMA16(0); BAR();
        LOADA(0, 0, 1);              STAGE(An, 0);  BAR(); MFMA16(1); BAR();
        LOADB(0, 1); LOADA(0, 1, 0); STAGE(An, 1);  BAR(); MFMA16(0); BAR();
        LOADA(0, 1, 1);              STAGE(An, 2);  BAR(); MFMA16(1);
        VMCNT6(); BAR();             // landed through s63 (K-tile 15 complete)
        LOADB(1, 0); LOADA(1, 0, 0); STAGE(An, 3);  BAR(); MFMA16(0); BAR();
        LOADA(1, 0, 1);              STAGE(An, 4);  BAR(); MFMA16(1); BAR();
        LOADB(1, 1); LOADA(1, 1, 0); STAGE(An, 5);  BAR(); MFMA16(0); BAR();
        LOADA(1, 1, 1);              STAGE(An, 6);  BAR(); MFMA16(1);
        VMCNT6(); BAR();             // landed through n3 (next K-tile 0 ready)

        // Epilogue tile r: NONTEMPORAL stores (don't evict xg/vb from L2/L3).
        const int c_row0 = (btm0 + 2 * r) * 256 + wr * 128 + lg * 4;
#pragma unroll
        for (int mi = 0; mi < 8; ++mi) {
            const int row = c_row0 + (mi >> 2) * 64 + (mi & 3) * 16;
#pragma unroll
            for (int n = 0; n < 4; ++n) {
#pragma unroll
                for (int j = 0; j < 4; ++j)
                    __builtin_nontemporal_store(acc[mi][n][j] + bvr[n],
                        &C[(size_t)(row + j) * NDIM + c_col0 + n * 16]);
                acc[mi][n] = (f32x4){0.f, 0.f, 0.f, 0.f};
            }
        }
    }
}

extern "C" void kernel_launch(void* const* d_in, const int* in_sizes, int n_in,
                              void* d_out, int out_size, void* d_ws, size_t ws_size,
                              hipStream_t stream) {
    const float* x      = (const float*)d_in[0];
    const float* values = (const float*)d_in[1];
    const float* bias   = (const float*)d_in[2];
    float* out = (float*)d_out;

    // ws: xg bf16 [16384][1024] = 32 MB @ 0; values bf16 [4096][1024] @ 32 MB
    u16* xg = (u16*)d_ws;
    u16* vb = (u16*)((char*)d_ws + ((size_t)32 << 20));

    prep_kernel<<<6144, 256, 0, stream>>>(x, (uint2*)xg, values, (uint4*)vb);
    gemm_kernel<<<256, 512, 0, stream>>>(xg, vb, bias, out);
}